// Round 1
// baseline (98.421 us; speedup 1.0000x reference)
//
#include <hip/hip_runtime.h>

// Problem constants (match reference)
#define NPIX   4000000
#define NPATHS 4000
#define PPI    500      // paths per image
#define HH     1024
#define WW     1024
#define BB     8
#define CAP    4096     // LDS value cache per segment (16 KB)
#define BLK    256

__device__ __forceinline__ float wave_reduce(float v) {
#pragma unroll
    for (int o = 32; o > 0; o >>= 1) v += __shfl_down(v, o);
    return v;
}

// One thread per segment boundary: lower_bound into sorted seg_ids.
__global__ void bounds_kernel(const int* __restrict__ seg, int* __restrict__ bounds) {
    int s = blockIdx.x * blockDim.x + threadIdx.x;
    if (s > NPATHS) return;
    if (s == NPATHS) { bounds[s] = NPIX; return; }
    int lo = 0, hi = NPIX;
    while (lo < hi) {
        int mid = (lo + hi) >> 1;
        if (seg[mid] < s) lo = mid + 1; else hi = mid;
    }
    bounds[s] = lo;
}

// One block per segment: gather vals, mean, then L1 deviation, one atomicAdd.
__global__ __launch_bounds__(BLK) void seg_loss_kernel(
    const float* __restrict__ input, const int* __restrict__ rows,
    const int* __restrict__ cols, const int* __restrict__ bounds,
    float* __restrict__ out)
{
    __shared__ float vals[CAP];
    __shared__ float red1[BLK / 64];
    __shared__ float red2[BLK / 64];
    __shared__ float bmean;

    const int s = blockIdx.x;
    const int start = bounds[s];
    const int end   = bounds[s + 1];
    const int n     = end - start;
    if (n <= 0) return;  // empty segment contributes 0 (count clamped to 1, sum 0)

    const float* __restrict__ img = input + (s / PPI) * (HH * WW);
    const int t = threadIdx.x;
    const bool fits = (n <= CAP);

    // Pass 1: gather + sum (cache values in LDS when they fit)
    float lsum = 0.f;
    for (int i = start + t; i < end; i += BLK) {
        float v = img[rows[i] * WW + cols[i]];
        if (fits) vals[i - start] = v;
        lsum += v;
    }
    float wsum = wave_reduce(lsum);
    if ((t & 63) == 0) red1[t >> 6] = wsum;
    __syncthreads();
    if (t == 0) {
        float tot = red1[0];
#pragma unroll
        for (int i = 1; i < BLK / 64; ++i) tot += red1[i];
        bmean = tot / (float)n;
    }
    __syncthreads();
    const float mean = bmean;

    // Pass 2: L1 deviation (from LDS cache, or re-gather in the rare oversize case)
    float ldev = 0.f;
    if (fits) {
        for (int li = t; li < n; li += BLK) ldev += fabsf(vals[li] - mean);
    } else {
        for (int i = start + t; i < end; i += BLK)
            ldev += fabsf(img[rows[i] * WW + cols[i]] - mean);
    }
    float wdev = wave_reduce(ldev);
    if ((t & 63) == 0) red2[t >> 6] = wdev;
    __syncthreads();
    if (t == 0) {
        float tot = red2[0];
#pragma unroll
        for (int i = 1; i < BLK / 64; ++i) tot += red2[i];
        atomicAdd(out, tot / (float)n * (1.0f / (float)BB));
    }
}

extern "C" void kernel_launch(void* const* d_in, const int* in_sizes, int n_in,
                              void* d_out, int out_size, void* d_ws, size_t ws_size,
                              hipStream_t stream) {
    const float* input = (const float*)d_in[0];
    const int* rows    = (const int*)d_in[1];
    const int* cols    = (const int*)d_in[2];
    const int* segs    = (const int*)d_in[3];
    float* out         = (float*)d_out;
    int* bounds        = (int*)d_ws;  // NPATHS+1 ints

    hipMemsetAsync(d_out, 0, sizeof(float), stream);
    bounds_kernel<<<(NPATHS + 1 + 255) / 256, 256, 0, stream>>>(segs, bounds);
    seg_loss_kernel<<<NPATHS, BLK, 0, stream>>>(input, rows, cols, bounds, out);
}

// Round 2
// 67.466 us; speedup vs baseline: 1.4588x; 1.4588x over previous
//
#include <hip/hip_runtime.h>

// Problem constants (match reference)
#define NPIX   4000000
#define NPATHS 4000
#define PPI    500      // paths per image
#define HH     1024
#define WW     1024
#define BB     8
#define CAP    4096     // LDS value cache per segment (16 KB)
#define BLK    256

__device__ __forceinline__ float wave_reduce(float v) {
#pragma unroll
    for (int o = 32; o > 0; o >>= 1) v += __shfl_down(v, o);
    return v;
}

// One thread per segment boundary: lower_bound into sorted seg_ids.
__global__ void bounds_kernel(const int* __restrict__ seg, int* __restrict__ bounds) {
    int s = blockIdx.x * blockDim.x + threadIdx.x;
    if (s > NPATHS) return;
    if (s == NPATHS) { bounds[s] = NPIX; return; }
    int lo = 0, hi = NPIX;
    while (lo < hi) {
        int mid = (lo + hi) >> 1;
        if (seg[mid] < s) lo = mid + 1; else hi = mid;
    }
    bounds[s] = lo;
}

// One block per segment: gather vals (4-way ILP), mean, L1 deviation.
// Writes per-segment loss to ws array — NO shared atomics.
__global__ __launch_bounds__(BLK) void seg_loss_kernel(
    const float* __restrict__ input, const int* __restrict__ rows,
    const int* __restrict__ cols, const int* __restrict__ bounds,
    float* __restrict__ loss)
{
    __shared__ float vals[CAP];
    __shared__ float red1[BLK / 64];
    __shared__ float red2[BLK / 64];
    __shared__ float bmean;

    const int s = blockIdx.x;
    const int start = bounds[s];
    const int end   = bounds[s + 1];
    const int n     = end - start;
    const int t = threadIdx.x;
    if (n <= 0) { if (t == 0) loss[s] = 0.f; return; }

    const float* __restrict__ img = input + (s / PPI) * (HH * WW);
    const bool fits = (n <= CAP);

    // Pass 1: gather + sum, 4 independent gathers in flight per thread.
    float lsum = 0.f;
    for (int i0 = start + t * 4; i0 < end; i0 += BLK * 4) {
        const int m = min(4, end - i0);
        int r[4], c[4];
        float v[4];
#pragma unroll
        for (int u = 0; u < 4; ++u)
            if (u < m) { r[u] = rows[i0 + u]; c[u] = cols[i0 + u]; }
#pragma unroll
        for (int u = 0; u < 4; ++u)
            if (u < m) v[u] = img[r[u] * WW + c[u]];
#pragma unroll
        for (int u = 0; u < 4; ++u)
            if (u < m) {
                if (fits) vals[i0 - start + u] = v[u];
                lsum += v[u];
            }
    }
    float wsum = wave_reduce(lsum);
    if ((t & 63) == 0) red1[t >> 6] = wsum;
    __syncthreads();
    if (t == 0) {
        float tot = red1[0];
#pragma unroll
        for (int i = 1; i < BLK / 64; ++i) tot += red1[i];
        bmean = tot / (float)n;
    }
    __syncthreads();
    const float mean = bmean;

    // Pass 2: L1 deviation (LDS cache, or re-gather in the rare oversize case)
    float ldev = 0.f;
    if (fits) {
        for (int li = t; li < n; li += BLK) ldev += fabsf(vals[li] - mean);
    } else {
        for (int i0 = start + t * 4; i0 < end; i0 += BLK * 4) {
            const int m = min(4, end - i0);
            int r[4], c[4];
            float v[4];
#pragma unroll
            for (int u = 0; u < 4; ++u)
                if (u < m) { r[u] = rows[i0 + u]; c[u] = cols[i0 + u]; }
#pragma unroll
            for (int u = 0; u < 4; ++u)
                if (u < m) v[u] = img[r[u] * WW + c[u]];
#pragma unroll
            for (int u = 0; u < 4; ++u)
                if (u < m) ldev += fabsf(v[u] - mean);
        }
    }
    float wdev = wave_reduce(ldev);
    if ((t & 63) == 0) red2[t >> 6] = wdev;
    __syncthreads();
    if (t == 0) {
        float tot = red2[0];
#pragma unroll
        for (int i = 1; i < BLK / 64; ++i) tot += red2[i];
        loss[s] = tot / (float)n;
    }
}

// Single block: sum the 4000 per-segment losses, divide by B, write scalar.
__global__ __launch_bounds__(BLK) void final_reduce(
    const float* __restrict__ loss, float* __restrict__ out)
{
    __shared__ float red[BLK / 64];
    float l = 0.f;
    for (int i = threadIdx.x; i < NPATHS; i += BLK) l += loss[i];
    float w = wave_reduce(l);
    if ((threadIdx.x & 63) == 0) red[threadIdx.x >> 6] = w;
    __syncthreads();
    if (threadIdx.x == 0) {
        float tot = 0.f;
#pragma unroll
        for (int i = 1; i < BLK / 64; ++i) tot += red[i];
        tot += red[0];
        out[0] = tot * (1.0f / (float)BB);
    }
}

extern "C" void kernel_launch(void* const* d_in, const int* in_sizes, int n_in,
                              void* d_out, int out_size, void* d_ws, size_t ws_size,
                              hipStream_t stream) {
    const float* input = (const float*)d_in[0];
    const int* rows    = (const int*)d_in[1];
    const int* cols    = (const int*)d_in[2];
    const int* segs    = (const int*)d_in[3];
    float* out         = (float*)d_out;
    int* bounds        = (int*)d_ws;                        // NPATHS+1 ints
    float* loss        = (float*)d_ws + (NPATHS + 1);       // NPATHS floats

    bounds_kernel<<<(NPATHS + 1 + 255) / 256, 256, 0, stream>>>(segs, bounds);
    seg_loss_kernel<<<NPATHS, BLK, 0, stream>>>(input, rows, cols, bounds, loss);
    final_reduce<<<1, BLK, 0, stream>>>(loss, out);
}

// Round 3
// 44.962 us; speedup vs baseline: 2.1890x; 1.5005x over previous
//
#include <hip/hip_runtime.h>

// Problem constants (match reference)
#define NPIX   4000000
#define NPATHS 4000
#define PPI    500      // paths per image
#define HH     1024
#define WW     1024
#define BB     8
#define CAP    2048     // LDS value cache per segment (8 KB; n ~ 1000 +- 32)
#define BLK    256
#define NXCD   8

__device__ __forceinline__ float wave_reduce(float v) {
#pragma unroll
    for (int o = 32; o > 0; o >>= 1) v += __shfl_down(v, o);
    return v;
}

// One WAVE per segment boundary: 64-ary cooperative lower_bound (4 probe
// rounds instead of 22 dependent scalar steps).
__global__ __launch_bounds__(256) void bounds_kernel(
    const int* __restrict__ seg, int* __restrict__ bounds)
{
    const int s    = blockIdx.x * 4 + (threadIdx.x >> 6);
    const int lane = threadIdx.x & 63;
    if (s > NPATHS) return;
    if (s == NPATHS) { if (lane == 0) bounds[s] = NPIX; return; }

    int lo = 0, hi = NPIX;          // answer in [lo, hi]
    while (hi > lo) {
        const int step = (hi - lo + 63) >> 6;
        const int pos  = lo + lane * step;
        const int x    = (pos < hi) ? seg[pos] : 0x7fffffff;
        const unsigned long long m = __ballot(x < s);
        const int c = __popcll(m);   // prefix count (sorted)
        if (c == 0) { hi = lo; break; }
        const int nlo = lo + (c - 1) * step + 1;
        const int nhi = (c < 64) ? min(hi, lo + c * step) : hi;
        lo = nlo; hi = nhi;
    }
    if (lane == 0) bounds[s] = lo;
}

// One block per segment. Block->segment map pins each image to one XCD:
// blocks with b%8==x all process image x, whose 4 MB fits that XCD's L2.
__global__ __launch_bounds__(BLK) void seg_loss_kernel(
    const float* __restrict__ input, const int* __restrict__ rows,
    const int* __restrict__ cols, const int* __restrict__ bounds,
    float* __restrict__ loss)
{
    __shared__ float vals[CAP];
    __shared__ float red1[BLK / 64];
    __shared__ float red2[BLK / 64];
    __shared__ float bmean;

    const int b = blockIdx.x;
    const int s = (b & (NXCD - 1)) * PPI + (b >> 3);   // XCD-pinned mapping
    const int start = bounds[s];
    const int end   = bounds[s + 1];
    const int n     = end - start;
    const int t = threadIdx.x;
    if (n <= 0) { if (t == 0) loss[s] = 0.f; return; }

    const float* __restrict__ img = input + (s / PPI) * (HH * WW);
    const bool fits = (n <= CAP);

    // Pass 1: gather + sum. int4 index loads, 4 gathers in flight per thread.
    const int start4 = start & ~3;
    float lsum = 0.f;
    for (int i0 = start4 + t * 4; i0 < end; i0 += BLK * 4) {
        int r[4], c[4];
        if (i0 >= start && i0 + 4 <= end) {          // aligned full group
            const int4 rr = *(const int4*)&rows[i0];
            const int4 cc = *(const int4*)&cols[i0];
            r[0] = rr.x; r[1] = rr.y; r[2] = rr.z; r[3] = rr.w;
            c[0] = cc.x; c[1] = cc.y; c[2] = cc.z; c[3] = cc.w;
            float v[4];
#pragma unroll
            for (int u = 0; u < 4; ++u) v[u] = img[r[u] * WW + c[u]];
#pragma unroll
            for (int u = 0; u < 4; ++u) {
                if (fits) vals[i0 - start + u] = v[u];
                lsum += v[u];
            }
        } else {                                      // segment edges
#pragma unroll
            for (int u = 0; u < 4; ++u) {
                const int j = i0 + u;
                if (j >= start && j < end) {
                    const float v = img[rows[j] * WW + cols[j]];
                    if (fits) vals[j - start] = v;
                    lsum += v;
                }
            }
        }
    }
    float wsum = wave_reduce(lsum);
    if ((t & 63) == 0) red1[t >> 6] = wsum;
    __syncthreads();
    if (t == 0) {
        float tot = red1[0];
#pragma unroll
        for (int i = 1; i < BLK / 64; ++i) tot += red1[i];
        bmean = tot / (float)n;
    }
    __syncthreads();
    const float mean = bmean;

    // Pass 2: L1 deviation from the LDS cache (fallback re-gather if oversize)
    float ldev = 0.f;
    if (fits) {
        for (int li = t; li < n; li += BLK) ldev += fabsf(vals[li] - mean);
    } else {
        for (int j = start + t; j < end; j += BLK)
            ldev += fabsf(img[rows[j] * WW + cols[j]] - mean);
    }
    float wdev = wave_reduce(ldev);
    if ((t & 63) == 0) red2[t >> 6] = wdev;
    __syncthreads();
    if (t == 0) {
        float tot = red2[0];
#pragma unroll
        for (int i = 1; i < BLK / 64; ++i) tot += red2[i];
        loss[s] = tot / (float)n;
    }
}

// Single block: sum the 4000 per-segment losses, divide by B, write scalar.
__global__ __launch_bounds__(BLK) void final_reduce(
    const float* __restrict__ loss, float* __restrict__ out)
{
    __shared__ float red[BLK / 64];
    float l = 0.f;
    for (int i = threadIdx.x; i < NPATHS; i += BLK) l += loss[i];
    float w = wave_reduce(l);
    if ((threadIdx.x & 63) == 0) red[threadIdx.x >> 6] = w;
    __syncthreads();
    if (threadIdx.x == 0) {
        float tot = 0.f;
#pragma unroll
        for (int i = 0; i < BLK / 64; ++i) tot += red[i];
        out[0] = tot * (1.0f / (float)BB);
    }
}

extern "C" void kernel_launch(void* const* d_in, const int* in_sizes, int n_in,
                              void* d_out, int out_size, void* d_ws, size_t ws_size,
                              hipStream_t stream) {
    const float* input = (const float*)d_in[0];
    const int* rows    = (const int*)d_in[1];
    const int* cols    = (const int*)d_in[2];
    const int* segs    = (const int*)d_in[3];
    float* out         = (float*)d_out;
    int* bounds        = (int*)d_ws;                        // NPATHS+1 ints
    float* loss        = (float*)d_ws + (NPATHS + 1);       // NPATHS floats

    bounds_kernel<<<(NPATHS + 1 + 3) / 4, 256, 0, stream>>>(segs, bounds);
    seg_loss_kernel<<<NPATHS, BLK, 0, stream>>>(input, rows, cols, bounds, loss);
    final_reduce<<<1, BLK, 0, stream>>>(loss, out);
}